// Round 3
// baseline (273.154 us; speedup 1.0000x reference)
//
#include <hip/hip_runtime.h>
#include <hip/hip_cooperative_groups.h>
#include <math.h>

namespace cg = cooperative_groups;

#define B_TOT 4096
#define B_HALF 2048
#define NBLK 256

// ws float offsets
#define ZT_OFF     0          // 4096*64 zt fp32
#define S_OFF      262144     // 4096: e_r = exp(s_r) per row
#define PSTAT_OFF  266240     // 256 blocks * 65 (E_b, T_b[64])
#define ZWB_OFF    524288     // bf16 4096*128
#define PREDB_OFF  786432     // bf16 4096*128
#define PART_OFF   1048576    // 4096 rows * 4 chunks * (m,s)
#define ACC_OFF    1081344    // 1 float loss accumulator

typedef __bf16 bf16x8 __attribute__((ext_vector_type(8)));
typedef float  f32x4  __attribute__((ext_vector_type(4)));

__device__ __forceinline__ unsigned short f2bf(float f) {
    unsigned u = __float_as_uint(f);
    u = u + 0x7fffu + ((u >> 16) & 1u);   // RNE
    return (unsigned short)(u >> 16);
}
__device__ __forceinline__ float bf2f(unsigned short h) {
    return __uint_as_float(((unsigned)h) << 16);
}

__global__ __launch_bounds__(256, 1)
void k_fused(const float* __restrict__ zw0, const float* __restrict__ zw1,
             const float* __restrict__ c,
             const float* __restrict__ Wk_w, const float* __restrict__ Wk_b,
             const float* __restrict__ Ww0_w, const float* __restrict__ Ww0_b,
             const float* __restrict__ Ww1_w, const float* __restrict__ Ww1_b,
             const float* __restrict__ lin0_w, const float* __restrict__ lin0_b,
             const float* __restrict__ lin1_w, const float* __restrict__ lin1_b,
             const float* __restrict__ a0_1w, const float* __restrict__ a0_1b,
             const float* __restrict__ a0_2w, const float* __restrict__ a0_2b,
             const float* __restrict__ a1_1w, const float* __restrict__ a1_1b,
             const float* __restrict__ a1_2w, const float* __restrict__ a1_2b,
             float* __restrict__ ws, float* __restrict__ out) {
    __shared__ float smem[20480];   // 80 KB, re-carved per phase
    cg::grid_group grid = cg::this_grid();
    int tid = threadIdx.x;
    int b = blockIdx.x;
    unsigned short* zwb   = (unsigned short*)(ws + ZWB_OFF);
    unsigned short* predb = (unsigned short*)(ws + PREDB_OFF);

    // ==================== P1: zt, e=exp(s), zw->bf16, block stats ============
    {
        float* lws = smem;              // 64*132
        float* zws = smem + 8448;       // 16*132
        float* ztl = smem + 10560;      // 16*68
        float* a1s = smem + 11648;      // 32*68
        float* el  = smem + 13824;      // 16
        int base = b * 16;
        int g = (base >= B_HALF);
        const float* lw = g ? lin1_w : lin0_w;
        const float* lb = g ? lin1_b : lin0_b;
        const float* w1 = g ? a1_1w : a0_1w;
        const float* b1 = g ? a1_1b : a0_1b;
        const float* w2 = g ? a1_2w : a0_2w;
        const float* b2 = g ? a1_2b : a0_2b;

        const float4* lw4 = (const float4*)lw;
        for (int i = tid; i < 2048; i += 256) {
            int o = i >> 5, k4 = i & 31;
            ((float4*)(lws + o * 132))[k4] = lw4[i];
        }
        for (int i = tid; i < 512; i += 256) {
            int r = i >> 5, k4 = i & 31;
            int gi = base + r;
            const float* zr = (gi < B_HALF) ? (zw0 + (size_t)gi * 128)
                                            : (zw1 + (size_t)(gi - B_HALF) * 128);
            float4 v = ((const float4*)zr)[k4];
            ((float4*)(zws + r * 132))[k4] = v;
            uint2 p;
            p.x = (unsigned)f2bf(v.x) | ((unsigned)f2bf(v.y) << 16);
            p.y = (unsigned)f2bf(v.z) | ((unsigned)f2bf(v.w) << 16);
            ((uint2*)(zwb + (size_t)gi * 128))[k4] = p;
        }
        const float4* w14 = (const float4*)w1;
        for (int i = tid; i < 512; i += 256) {
            int o = i >> 4, k4 = i & 15;
            ((float4*)(a1s + o * 68))[k4] = w14[i];
        }
        __syncthreads();

        int o = tid & 63, rgrp = tid >> 6;
        {
            float bias = lb[o];
            float acc[4] = {bias, bias, bias, bias};
            const float4* wrow = (const float4*)(lws + o * 132);
            const float4* zr0 = (const float4*)(zws + (rgrp + 0) * 132);
            const float4* zr1 = (const float4*)(zws + (rgrp + 4) * 132);
            const float4* zr2 = (const float4*)(zws + (rgrp + 8) * 132);
            const float4* zr3 = (const float4*)(zws + (rgrp + 12) * 132);
#pragma unroll 4
            for (int k4 = 0; k4 < 32; ++k4) {
                float4 wv = wrow[k4];
                float4 z0 = zr0[k4], z1 = zr1[k4], z2 = zr2[k4], z3 = zr3[k4];
                acc[0] = fmaf(wv.x, z0.x, fmaf(wv.y, z0.y, fmaf(wv.z, z0.z, fmaf(wv.w, z0.w, acc[0]))));
                acc[1] = fmaf(wv.x, z1.x, fmaf(wv.y, z1.y, fmaf(wv.z, z1.z, fmaf(wv.w, z1.w, acc[1]))));
                acc[2] = fmaf(wv.x, z2.x, fmaf(wv.y, z2.y, fmaf(wv.z, z2.z, fmaf(wv.w, z2.w, acc[2]))));
                acc[3] = fmaf(wv.x, z3.x, fmaf(wv.y, z3.y, fmaf(wv.z, z3.z, fmaf(wv.w, z3.w, acc[3]))));
            }
#pragma unroll
            for (int rr = 0; rr < 4; ++rr) {
                int row = rgrp + rr * 4;
                float zt = fmaxf(acc[rr], 0.f);
                ztl[row * 68 + o] = zt;
                ws[ZT_OFF + (size_t)(base + row) * 64 + o] = zt;
            }
        }
        __syncthreads();

        int o2 = tid & 31, r2 = tid >> 5;
        const float4* arow = (const float4*)(a1s + o2 * 68);
#pragma unroll
        for (int rpass = 0; rpass < 2; ++rpass) {
            int row = r2 + rpass * 8;
            float a = b1[o2];
            const float4* zt4 = (const float4*)(ztl + row * 68);
#pragma unroll 4
            for (int k4 = 0; k4 < 16; ++k4) {
                float4 wv = arow[k4];
                float4 zv = zt4[k4];
                a = fmaf(wv.x, zv.x, fmaf(wv.y, zv.y, fmaf(wv.z, zv.z, fmaf(wv.w, zv.w, a))));
            }
            float h = tanhf(a) * w2[o2];
#pragma unroll
            for (int mask = 16; mask > 0; mask >>= 1) h += __shfl_xor(h, mask);
            if (o2 == 0) {
                // |s| <= |b2| + sum|w2| ~ 5 -> exp safe in fp32 without max-sub
                float e = __expf(h + b2[0]);
                el[row] = e;
                ws[S_OFF + base + row] = e;
            }
        }
        __syncthreads();

        if (tid < 64) {
            float t = 0.f;
#pragma unroll
            for (int r = 0; r < 16; ++r) t = fmaf(el[r], ztl[r * 68 + tid], t);
            ws[PSTAT_OFF + b * 65 + 1 + tid] = t;
        }
        if (tid == 64) {
            float E = 0.f;
#pragma unroll
            for (int r = 0; r < 16; ++r) E += el[r];
            ws[PSTAT_OFF + b * 65] = E;
        }
        if (b == 0 && tid == 0) ws[ACC_OFF] = 0.f;
    }
    grid.sync();

    // ==================== P2: pooled -> pred (bf16) ==========================
    {
        float* Wws = smem;              // 128*68
        float* Wks = smem + 8704;       // 128*68
        float* pl  = smem + 17408;      // 16*68
        float* cl  = smem + 18496;      // 16*68
        float* Ts  = smem + 19584;      // 65 (E, T[64])
        int base = b * 16;
        int g = (b >= 128);
        const float* Ww  = g ? Ww1_w : Ww0_w;
        const float* Wwb = g ? Ww1_b : Ww0_b;

        const float4* Ww4 = (const float4*)Ww;
        const float4* Wk4 = (const float4*)Wk_w;
        for (int i = tid; i < 2048; i += 256) {
            int o = i >> 4, k4 = i & 15;
            ((float4*)(Wws + o * 68))[k4] = Ww4[i];
            ((float4*)(Wks + o * 68))[k4] = Wk4[i];
        }
        if (tid < 256) {
            int r = tid >> 4, k4 = tid & 15;
            ((float4*)(cl + r * 68))[k4] = ((const float4*)(c + (size_t)(base + r) * 64))[k4];
        }
        if (tid < 65) {
            float t = 0.f;
            const float* ps = ws + PSTAT_OFF + (size_t)g * 128 * 65 + tid;
            for (int q = 0; q < 128; ++q) t += ps[(size_t)q * 65];
            Ts[tid] = t;
        }
        __syncthreads();
        for (int i = tid; i < 1024; i += 256) {
            int r = i >> 6, k = i & 63;
            float er = ws[S_OFF + base + r];
            pl[r * 68 + k] = (Ts[1 + k] - er * ws[ZT_OFF + (size_t)(base + r) * 64 + k])
                             / (Ts[0] - er);
        }
        __syncthreads();

        int o = tid & 127, rsel = tid >> 7;
        float bias = Wwb[o] + Wk_b[o];
        float acc[8] = {bias, bias, bias, bias, bias, bias, bias, bias};
        const float4* wrow = (const float4*)(Wws + o * 68);
        const float4* krow = (const float4*)(Wks + o * 68);
#pragma unroll 4
        for (int k4 = 0; k4 < 16; ++k4) {
            float4 wv = wrow[k4];
#pragma unroll
            for (int j = 0; j < 8; ++j) {
                float4 pv = ((const float4*)(pl + (rsel + j * 2) * 68))[k4];
                acc[j] = fmaf(wv.x, pv.x, fmaf(wv.y, pv.y, fmaf(wv.z, pv.z, fmaf(wv.w, pv.w, acc[j]))));
            }
        }
#pragma unroll 4
        for (int k4 = 0; k4 < 16; ++k4) {
            float4 kv = krow[k4];
#pragma unroll
            for (int j = 0; j < 8; ++j) {
                float4 cv = ((const float4*)(cl + (rsel + j * 2) * 68))[k4];
                acc[j] = fmaf(kv.x, cv.x, fmaf(kv.y, cv.y, fmaf(kv.z, cv.z, fmaf(kv.w, cv.w, acc[j]))));
            }
        }
#pragma unroll
        for (int j = 0; j < 8; ++j)
            predb[(size_t)(base + rsel + j * 2) * 128 + o] = f2bf(acc[j]);
    }
    grid.sync();

    // ==================== P3: MFMA logits + online lse partials ==============
    {
        int it = b >> 2, jg = b & 3;   // i-tile 0..63, j-group (16 j-tiles)
        unsigned short* sm16 = (unsigned short*)smem;
        unsigned short* zs = sm16;                       // 64 x 136
        unsigned short* ps0 = sm16 + 8704;
        unsigned short* ps1 = sm16 + 17408;

        for (int i = tid; i < 1024; i += 256) {
            int r = i >> 4, gq = i & 15;
            ((float4*)(zs + r * 136))[gq] =
                ((const float4*)(zwb + (size_t)(it * 64 + r) * 128))[gq];
            ((float4*)(ps0 + r * 136))[gq] =
                ((const float4*)(predb + (size_t)(jg * 1024 + r) * 128))[gq];
        }
        __syncthreads();

        int lane = tid & 63, w = tid >> 6;
        int m16 = lane & 15, quad = lane >> 4;

        bf16x8 af[4];
#pragma unroll
        for (int kk = 0; kk < 4; ++kk)
            af[kk] = *((const bf16x8*)(zs + (w * 16 + m16) * 136 + kk * 32 + quad * 8));

        float m_run[4], s_run[4];
#pragma unroll
        for (int r = 0; r < 4; ++r) { m_run[r] = -INFINITY; s_run[r] = 0.f; }

        for (int jt = 0; jt < 16; ++jt) {
            unsigned short* cur = (jt & 1) ? ps1 : ps0;
            unsigned short* nxt = (jt & 1) ? ps0 : ps1;
            if (jt < 15) {
                int j0 = jg * 1024 + (jt + 1) * 64;
                for (int i = tid; i < 1024; i += 256) {
                    int r = i >> 4, gq = i & 15;
                    ((float4*)(nxt + r * 136))[gq] =
                        ((const float4*)(predb + (size_t)(j0 + r) * 128))[gq];
                }
            }
            f32x4 acc[4];
#pragma unroll
            for (int b4 = 0; b4 < 4; ++b4) {
                acc[b4] = (f32x4){0.f, 0.f, 0.f, 0.f};
#pragma unroll
                for (int kk = 0; kk < 4; ++kk) {
                    bf16x8 bf = *((const bf16x8*)(cur + (b4 * 16 + m16) * 136 + kk * 32 + quad * 8));
                    acc[b4] = __builtin_amdgcn_mfma_f32_16x16x32_bf16(af[kk], bf, acc[b4], 0, 0, 0);
                }
            }
#pragma unroll
            for (int r = 0; r < 4; ++r) {
                float vm = fmaxf(fmaxf(acc[0][r], acc[1][r]), fmaxf(acc[2][r], acc[3][r]));
                float mn = fmaxf(m_run[r], vm);
                float add = __expf(acc[0][r] - mn) + __expf(acc[1][r] - mn) +
                            __expf(acc[2][r] - mn) + __expf(acc[3][r] - mn);
                s_run[r] = s_run[r] * __expf(m_run[r] - mn) + add;
                m_run[r] = mn;
            }
            __syncthreads();
        }

#pragma unroll
        for (int r = 0; r < 4; ++r) {
            float m = m_run[r], s = s_run[r];
#pragma unroll
            for (int mask = 1; mask < 16; mask <<= 1) {
                float om = __shfl_xor(m, mask);
                float os = __shfl_xor(s, mask);
                float mn = fmaxf(m, om);
                s = s * __expf(m - mn) + os * __expf(om - mn);
                m = mn;
            }
            if (m16 == 0) {
                int gi = it * 64 + w * 16 + quad * 4 + r;
                ws[PART_OFF + (size_t)gi * 8 + jg * 2]     = m;
                ws[PART_OFF + (size_t)gi * 8 + jg * 2 + 1] = s;
            }
        }
    }
    grid.sync();

    // ==================== P4: row lse merge + diag + loss reduce =============
    {
        float* rv = smem;   // 16
        int r16 = tid >> 4, s16 = tid & 15;
        int gi = b * 16 + r16;
        const uint4 za = *((const uint4*)(zwb   + (size_t)gi * 128 + s16 * 8));
        const uint4 pa = *((const uint4*)(predb + (size_t)gi * 128 + s16 * 8));
        float d = 0.f;
        const unsigned* zu = (const unsigned*)&za;
        const unsigned* pu = (const unsigned*)&pa;
#pragma unroll
        for (int q = 0; q < 4; ++q) {
            d = fmaf(bf2f((unsigned short)(zu[q] & 0xffff)),
                     bf2f((unsigned short)(pu[q] & 0xffff)), d);
            d = fmaf(bf2f((unsigned short)(zu[q] >> 16)),
                     bf2f((unsigned short)(pu[q] >> 16)), d);
        }
#pragma unroll
        for (int mask = 1; mask < 16; mask <<= 1) d += __shfl_xor(d, mask);
        if (s16 == 0) {
            float M = -INFINITY;
#pragma unroll
            for (int q = 0; q < 4; ++q)
                M = fmaxf(M, ws[PART_OFF + (size_t)gi * 8 + q * 2]);
            float S = 0.f;
#pragma unroll
            for (int q = 0; q < 4; ++q)
                S += ws[PART_OFF + (size_t)gi * 8 + q * 2 + 1] *
                     __expf(ws[PART_OFF + (size_t)gi * 8 + q * 2] - M);
            rv[r16] = d - (M + logf(S));
        }
        __syncthreads();
        if (tid == 0) {
            float bs = 0.f;
#pragma unroll
            for (int i = 0; i < 16; ++i) bs += rv[i];
            atomicAdd(ws + ACC_OFF, bs);
        }
    }
    grid.sync();

    if (b == 0 && tid == 0) {
        float acc = __hip_atomic_load(ws + ACC_OFF, __ATOMIC_RELAXED,
                                      __HIP_MEMORY_SCOPE_AGENT);
        out[0] = -acc / (float)B_TOT;
    }
}

extern "C" void kernel_launch(void* const* d_in, const int* in_sizes, int n_in,
                              void* d_out, int out_size, void* d_ws, size_t ws_size,
                              hipStream_t stream) {
    const float* zw_0   = (const float*)d_in[0];
    const float* zw_1   = (const float*)d_in[1];
    const float* c      = (const float*)d_in[2];
    const float* Wk_w   = (const float*)d_in[3];
    const float* Wk_b   = (const float*)d_in[4];
    const float* Ww0_w  = (const float*)d_in[5];
    const float* Ww0_b  = (const float*)d_in[6];
    const float* Ww1_w  = (const float*)d_in[7];
    const float* Ww1_b  = (const float*)d_in[8];
    const float* lin0_w = (const float*)d_in[9];
    const float* lin0_b = (const float*)d_in[10];
    const float* lin1_w = (const float*)d_in[11];
    const float* lin1_b = (const float*)d_in[12];
    const float* a0_1w  = (const float*)d_in[13];
    const float* a0_1b  = (const float*)d_in[14];
    const float* a0_2w  = (const float*)d_in[15];
    const float* a0_2b  = (const float*)d_in[16];
    const float* a1_1w  = (const float*)d_in[17];
    const float* a1_1b  = (const float*)d_in[18];
    const float* a1_2w  = (const float*)d_in[19];
    const float* a1_2b  = (const float*)d_in[20];
    float* ws  = (float*)d_ws;
    float* out = (float*)d_out;

    void* args[] = {
        (void*)&zw_0, (void*)&zw_1, (void*)&c,
        (void*)&Wk_w, (void*)&Wk_b,
        (void*)&Ww0_w, (void*)&Ww0_b, (void*)&Ww1_w, (void*)&Ww1_b,
        (void*)&lin0_w, (void*)&lin0_b, (void*)&lin1_w, (void*)&lin1_b,
        (void*)&a0_1w, (void*)&a0_1b, (void*)&a0_2w, (void*)&a0_2b,
        (void*)&a1_1w, (void*)&a1_1b, (void*)&a1_2w, (void*)&a1_2b,
        (void*)&ws, (void*)&out
    };
    hipLaunchCooperativeKernel((void*)k_fused, dim3(NBLK), dim3(256),
                               args, 0, stream);
}

// Round 5
// 175.015 us; speedup vs baseline: 1.5607x; 1.5607x over previous
//
#include <hip/hip_runtime.h>
#include <math.h>

#define B_TOT 4096
#define B_HALF 2048

// ws float offsets.  NOTE: bf16 4096x128 = 524288 halves = 262144 FLOATS.
#define ZWB_OFF    0          // bf16 4096*128  -> [0, 262144)
#define EV_OFF     262144     // 4096: e_i = exp(s_i)
#define VV_OFF     266240     // 4096*128 f32: v_i = zt_i @ Ww^T -> [.., 790528)
#define BASE_OFF   790528     // 4096*128 f32: c_i@Wk^T + Wk_b + Ww_b -> [.., 1314816)
#define PSTAT_OFF  1314816    // 256 blocks * 129 (E_b, U_b[128]) -> [.., 1347840)
#define PREDB_OFF  1347840    // bf16 4096*128 -> [.., 1609984)
#define DIAG_OFF   1609984    // 4096 -> [.., 1614080)
#define ACC_OFF    1614080
#define TICKET_OFF 1614081

typedef __bf16 bf16x8 __attribute__((ext_vector_type(8)));
typedef float  f32x4  __attribute__((ext_vector_type(4)));

__device__ __forceinline__ unsigned short f2bf(float f) {
    unsigned u = __float_as_uint(f);
    u = u + 0x7fffu + ((u >> 16) & 1u);   // RNE
    return (unsigned short)(u >> 16);
}
__device__ __forceinline__ float bf2f(unsigned short h) {
    return __uint_as_float(((unsigned)h) << 16);
}

// ---------------------------------------------------------------------------
// K1: per 16-row block: zt=relu(zw@lw^T+lb) (LDS only), e=exp(score),
// v = zt@Ww^T -> VV, base = c@Wk^T + Wk_b + Ww_b -> BASE, zw->bf16,
// block partials (E_b, U_b = sum e*v) -> PSTAT. No atomics.
// ---------------------------------------------------------------------------
__global__ __launch_bounds__(256)
void k1(const float* __restrict__ zw0, const float* __restrict__ zw1,
        const float* __restrict__ c,
        const float* __restrict__ Wk_w, const float* __restrict__ Wk_b,
        const float* __restrict__ Ww0_w, const float* __restrict__ Ww0_b,
        const float* __restrict__ Ww1_w, const float* __restrict__ Ww1_b,
        const float* __restrict__ lin0_w, const float* __restrict__ lin0_b,
        const float* __restrict__ lin1_w, const float* __restrict__ lin1_b,
        const float* __restrict__ a0_1w, const float* __restrict__ a0_1b,
        const float* __restrict__ a0_2w, const float* __restrict__ a0_2b,
        const float* __restrict__ a1_1w, const float* __restrict__ a1_1b,
        const float* __restrict__ a1_2w, const float* __restrict__ a1_2b,
        float* __restrict__ ws) {
    __shared__ float lws[8448];    // lin_w 64x132
    __shared__ float zws[2112];    // zw 16x132
    __shared__ float ztl[1088];    // zt 16x68
    __shared__ float a1s[2176];    // a1w 32x68
    __shared__ float wbuf[8704];   // Wk then Ww, 128x68
    __shared__ float cl[1088];     // c 16x68
    __shared__ float el[16];
    __shared__ float part[256];
    int tid = threadIdx.x;
    int b = blockIdx.x;
    int base = b * 16;
    int g = (base >= B_HALF);
    const float* lw = g ? lin1_w : lin0_w;
    const float* lb = g ? lin1_b : lin0_b;
    const float* w1 = g ? a1_1w : a0_1w;
    const float* b1 = g ? a1_1b : a0_1b;
    const float* w2 = g ? a1_2w : a0_2w;
    const float* b2 = g ? a1_2b : a0_2b;
    const float* Ww  = g ? Ww1_w : Ww0_w;
    const float* Wwb = g ? Ww1_b : Ww0_b;
    unsigned short* zwb = (unsigned short*)(ws + ZWB_OFF);

    // ---- stage: lin_w, zw(+bf16 cast), a1w, c, Wk ----
    const float4* lw4 = (const float4*)lw;
    for (int i = tid; i < 2048; i += 256) {
        int o = i >> 5, k4 = i & 31;
        ((float4*)(lws + o * 132))[k4] = lw4[i];
    }
    for (int i = tid; i < 512; i += 256) {
        int r = i >> 5, k4 = i & 31;
        int gi = base + r;
        const float* zr = (gi < B_HALF) ? (zw0 + (size_t)gi * 128)
                                        : (zw1 + (size_t)(gi - B_HALF) * 128);
        float4 v = ((const float4*)zr)[k4];
        ((float4*)(zws + r * 132))[k4] = v;
        uint2 p;
        p.x = (unsigned)f2bf(v.x) | ((unsigned)f2bf(v.y) << 16);
        p.y = (unsigned)f2bf(v.z) | ((unsigned)f2bf(v.w) << 16);
        ((uint2*)(zwb + (size_t)gi * 128))[k4] = p;
    }
    const float4* w14 = (const float4*)w1;
    for (int i = tid; i < 512; i += 256) {
        int o = i >> 4, k4 = i & 15;
        ((float4*)(a1s + o * 68))[k4] = w14[i];
    }
    if (tid < 256) {
        int r = tid >> 4, k4 = tid & 15;
        ((float4*)(cl + r * 68))[k4] = ((const float4*)(c + (size_t)(base + r) * 64))[k4];
    }
    const float4* Wk4 = (const float4*)Wk_w;
    for (int i = tid; i < 2048; i += 256) {
        int o = i >> 4, k4 = i & 15;
        ((float4*)(wbuf + o * 68))[k4] = Wk4[i];
    }
    __syncthreads();

    // ---- zt: out o=tid&63, rows rgrp+{0,4,8,12} ----
    {
        int o = tid & 63, rgrp = tid >> 6;
        float bias = lb[o];
        float acc[4] = {bias, bias, bias, bias};
        const float4* wrow = (const float4*)(lws + o * 132);
        const float4* zr0 = (const float4*)(zws + (rgrp + 0) * 132);
        const float4* zr1 = (const float4*)(zws + (rgrp + 4) * 132);
        const float4* zr2 = (const float4*)(zws + (rgrp + 8) * 132);
        const float4* zr3 = (const float4*)(zws + (rgrp + 12) * 132);
#pragma unroll 4
        for (int k4 = 0; k4 < 32; ++k4) {
            float4 wv = wrow[k4];
            float4 z0 = zr0[k4], z1 = zr1[k4], z2 = zr2[k4], z3 = zr3[k4];
            acc[0] = fmaf(wv.x, z0.x, fmaf(wv.y, z0.y, fmaf(wv.z, z0.z, fmaf(wv.w, z0.w, acc[0]))));
            acc[1] = fmaf(wv.x, z1.x, fmaf(wv.y, z1.y, fmaf(wv.z, z1.z, fmaf(wv.w, z1.w, acc[1]))));
            acc[2] = fmaf(wv.x, z2.x, fmaf(wv.y, z2.y, fmaf(wv.z, z2.z, fmaf(wv.w, z2.w, acc[2]))));
            acc[3] = fmaf(wv.x, z3.x, fmaf(wv.y, z3.y, fmaf(wv.z, z3.z, fmaf(wv.w, z3.w, acc[3]))));
        }
#pragma unroll
        for (int rr = 0; rr < 4; ++rr)
            ztl[(rgrp + rr * 4) * 68 + o] = fmaxf(acc[rr], 0.f);
    }
    __syncthreads();

    // ---- attention score -> e (no max-sub; |s| bounded small) ----
    {
        int o2 = tid & 31, r2 = tid >> 5;
        const float4* arow = (const float4*)(a1s + o2 * 68);
#pragma unroll
        for (int rpass = 0; rpass < 2; ++rpass) {
            int row = r2 + rpass * 8;
            float a = b1[o2];
            const float4* zt4 = (const float4*)(ztl + row * 68);
#pragma unroll 4
            for (int k4 = 0; k4 < 16; ++k4) {
                float4 wv = arow[k4];
                float4 zv = zt4[k4];
                a = fmaf(wv.x, zv.x, fmaf(wv.y, zv.y, fmaf(wv.z, zv.z, fmaf(wv.w, zv.w, a))));
            }
            float h = tanhf(a) * w2[o2];
#pragma unroll
            for (int mask = 16; mask > 0; mask >>= 1) h += __shfl_xor(h, mask);
            if (o2 == 0) {
                float e = __expf(h + b2[0]);
                el[row] = e;
                ws[EV_OFF + base + row] = e;
            }
        }
    }

    // ---- base = c@Wk^T + Wk_b + Ww_b (independent of ztl/el) ----
    {
        int o = tid & 127, rsel = tid >> 7;
        float bias = Wk_b[o] + Wwb[o];
        float acc[8] = {bias, bias, bias, bias, bias, bias, bias, bias};
        const float4* krow = (const float4*)(wbuf + o * 68);
#pragma unroll 4
        for (int k4 = 0; k4 < 16; ++k4) {
            float4 kv = krow[k4];
#pragma unroll
            for (int j = 0; j < 8; ++j) {
                float4 cv = ((const float4*)(cl + (rsel + j * 2) * 68))[k4];
                acc[j] = fmaf(kv.x, cv.x, fmaf(kv.y, cv.y, fmaf(kv.z, cv.z, fmaf(kv.w, cv.w, acc[j]))));
            }
        }
#pragma unroll
        for (int j = 0; j < 8; ++j)
            ws[BASE_OFF + (size_t)(base + rsel + j * 2) * 128 + o] = acc[j];
    }
    __syncthreads();

    // ---- restage wbuf <- Ww ----
    const float4* Ww4 = (const float4*)Ww;
    for (int i = tid; i < 2048; i += 256) {
        int o = i >> 4, k4 = i & 15;
        ((float4*)(wbuf + o * 68))[k4] = Ww4[i];
    }
    __syncthreads();

    // ---- v = zt@Ww^T -> VV; partial U_b = sum e*v ----
    {
        int o = tid & 127, rsel = tid >> 7;
        float acc[8] = {0.f, 0.f, 0.f, 0.f, 0.f, 0.f, 0.f, 0.f};
        const float4* wrow = (const float4*)(wbuf + o * 68);
#pragma unroll 4
        for (int k4 = 0; k4 < 16; ++k4) {
            float4 wv = wrow[k4];
#pragma unroll
            for (int j = 0; j < 8; ++j) {
                float4 pv = ((const float4*)(ztl + (rsel + j * 2) * 68))[k4];
                acc[j] = fmaf(wv.x, pv.x, fmaf(wv.y, pv.y, fmaf(wv.z, pv.z, fmaf(wv.w, pv.w, acc[j]))));
            }
        }
        float p = 0.f;
#pragma unroll
        for (int j = 0; j < 8; ++j) {
            ws[VV_OFF + (size_t)(base + rsel + j * 2) * 128 + o] = acc[j];
            p = fmaf(el[rsel + j * 2], acc[j], p);
        }
        part[tid] = p;
    }
    __syncthreads();
    if (tid < 128)
        ws[PSTAT_OFF + (size_t)b * 129 + 1 + tid] = part[tid] + part[tid + 128];
    if (tid == 128) {
        float E = 0.f;
#pragma unroll
        for (int r = 0; r < 16; ++r) E += el[r];
        ws[PSTAT_OFF + (size_t)b * 129] = E;
    }
}

// ---------------------------------------------------------------------------
// K2: reduce group partials (E,U[128]); pred = (U - e*v)/(E-e) + base -> bf16;
// diag[i] = dot(zw_i, pred_i). Block 0 zeroes ACC/TICKET for K3.
// ---------------------------------------------------------------------------
__global__ __launch_bounds__(256)
void k2(float* __restrict__ ws) {
    __shared__ float us[132];
    int tid = threadIdx.x;
    int b = blockIdx.x;
    int base = b * 16;
    int g = (b >= 128);
    unsigned short* zwb   = (unsigned short*)(ws + ZWB_OFF);
    unsigned short* predb = (unsigned short*)(ws + PREDB_OFF);

    if (tid < 129) {
        const float* ps = ws + PSTAT_OFF + (size_t)g * 128 * 129 + tid;
        float acc = 0.f;
#pragma unroll 8
        for (int q = 0; q < 128; ++q) acc += ps[(size_t)q * 129];
        us[tid] = acc;
    }
    if (b == 0 && tid == 200) {
        ws[ACC_OFF] = 0.f;
        ws[TICKET_OFF] = 0.f;
    }
    __syncthreads();

    float E = us[0];
    int r = tid >> 4, s16 = tid & 15;
    int gi = base + r;
    float er = ws[EV_OFF + gi];
    float inv = 1.f / (E - er);
    int o8 = s16 * 8;
    const float4* v4 = (const float4*)(ws + VV_OFF + (size_t)gi * 128 + o8);
    const float4* b4 = (const float4*)(ws + BASE_OFF + (size_t)gi * 128 + o8);
    float pr[8];
#pragma unroll
    for (int h = 0; h < 2; ++h) {
        float4 vv = v4[h], bb = b4[h];
        pr[h * 4 + 0] = (us[1 + o8 + h * 4 + 0] - er * vv.x) * inv + bb.x;
        pr[h * 4 + 1] = (us[1 + o8 + h * 4 + 1] - er * vv.y) * inv + bb.y;
        pr[h * 4 + 2] = (us[1 + o8 + h * 4 + 2] - er * vv.z) * inv + bb.z;
        pr[h * 4 + 3] = (us[1 + o8 + h * 4 + 3] - er * vv.w) * inv + bb.w;
    }
    uint4 pk;
    pk.x = (unsigned)f2bf(pr[0]) | ((unsigned)f2bf(pr[1]) << 16);
    pk.y = (unsigned)f2bf(pr[2]) | ((unsigned)f2bf(pr[3]) << 16);
    pk.z = (unsigned)f2bf(pr[4]) | ((unsigned)f2bf(pr[5]) << 16);
    pk.w = (unsigned)f2bf(pr[6]) | ((unsigned)f2bf(pr[7]) << 16);
    ((uint4*)(predb + (size_t)gi * 128))[s16] = pk;

    // diag partial: bf16 zw x fp32 pred
    uint4 zz = ((const uint4*)(zwb + (size_t)gi * 128))[s16];
    const unsigned* zu = (const unsigned*)&zz;
    float d = 0.f;
#pragma unroll
    for (int q = 0; q < 4; ++q) {
        d = fmaf(bf2f((unsigned short)(zu[q] & 0xffff)), pr[q * 2], d);
        d = fmaf(bf2f((unsigned short)(zu[q] >> 16)), pr[q * 2 + 1], d);
    }
#pragma unroll
    for (int mask = 8; mask > 0; mask >>= 1) d += __shfl_xor(d, mask);
    if (s16 == 0) ws[DIAG_OFF + gi] = d;
}

// ---------------------------------------------------------------------------
// K3: 64 blocks x 1024 thr. Block = 64-row i-stripe over ALL 4096 j.
// 4 wave-groups x 16 j-tiles, register-prefetch -> LDS, MFMA 16x16x32 bf16,
// online lse per row; merge; rowval = diag - lse; block sum -> ACC + ticket;
// last block writes out.
// ---------------------------------------------------------------------------
__global__ __launch_bounds__(1024, 1)
void k3(float* __restrict__ ws, float* __restrict__ out) {
    __shared__ unsigned short zs[8704];        // 64 x 136
    __shared__ unsigned short ps[4][8704];     // per-group tile
    __shared__ float2 part2[256];              // 64 rows x 4 groups
    int tid = threadIdx.x;
    int i0 = blockIdx.x * 64;
    const unsigned short* zwb   = (const unsigned short*)(ws + ZWB_OFF);
    const unsigned short* predb = (const unsigned short*)(ws + PREDB_OFF);

    {
        int r = tid >> 4, q = tid & 15;
        ((float4*)(zs + r * 136))[q] = ((const float4*)(zwb + (size_t)(i0 + r) * 128))[q];
    }

    int w = tid >> 6, lane = tid & 63;
    int g = w >> 2, wl = w & 3;
    int m16 = lane & 15, quad = lane >> 4;
    int tg = tid & 255;
    int prow = tg >> 2, pq4 = (tg & 3) * 4;
    unsigned short* psg = ps[g];

    // prefetch tile 0
    float4 pf[4];
    {
        const float4* src = (const float4*)(predb + (size_t)(g * 1024 + prow) * 128);
#pragma unroll
        for (int k = 0; k < 4; ++k) pf[k] = src[pq4 + k];
#pragma unroll
        for (int k = 0; k < 4; ++k) ((float4*)(psg + prow * 136))[pq4 + k] = pf[k];
    }
    __syncthreads();

    bf16x8 af[4];
#pragma unroll
    for (int kk = 0; kk < 4; ++kk)
        af[kk] = *((const bf16x8*)(zs + (wl * 16 + m16) * 136 + kk * 32 + quad * 8));

    float m_run[4], s_run[4];
#pragma unroll
    for (int r = 0; r < 4; ++r) { m_run[r] = -INFINITY; s_run[r] = 0.f; }

    for (int jt = 0; jt < 16; ++jt) {
        if (jt < 15) {
            const float4* src =
                (const float4*)(predb + (size_t)(g * 1024 + (jt + 1) * 64 + prow) * 128);
#pragma unroll
            for (int k = 0; k < 4; ++k) pf[k] = src[pq4 + k];
        }
        f32x4 acc[4];
#pragma unroll
        for (int b4 = 0; b4 < 4; ++b4) {
            acc[b4] = (f32x4){0.f, 0.f, 0.f, 0.f};
#pragma unroll
            for (int kk = 0; kk < 4; ++kk) {
                bf16x8 bf = *((const bf16x8*)(psg + (b4 * 16 + m16) * 136 + kk * 32 + quad * 8));
                acc[b4] = __builtin_amdgcn_mfma_f32_16x16x32_bf16(af[kk], bf, acc[b4], 0, 0, 0);
            }
        }
#pragma unroll
        for (int r = 0; r < 4; ++r) {
            float vm = fmaxf(fmaxf(acc[0][r], acc[1][r]), fmaxf(acc[2][r], acc[3][r]));
            float mn = fmaxf(m_run[r], vm);
            float add = __expf(acc[0][r] - mn) + __expf(acc[1][r] - mn) +
                        __expf(acc[2][r] - mn) + __expf(acc[3][r] - mn);
            s_run[r] = s_run[r] * __expf(m_run[r] - mn) + add;
            m_run[r] = mn;
        }
        __syncthreads();
        if (jt < 15) {
#pragma unroll
            for (int k = 0; k < 4; ++k) ((float4*)(psg + prow * 136))[pq4 + k] = pf[k];
        }
        __syncthreads();
    }

    // merge over m16 lanes
#pragma unroll
    for (int r = 0; r < 4; ++r) {
        float m = m_run[r], s = s_run[r];
#pragma unroll
        for (int mask = 1; mask < 16; mask <<= 1) {
            float om = __shfl_xor(m, mask);
            float os = __shfl_xor(s, mask);
            float mn = fmaxf(m, om);
            s = s * __expf(m - mn) + os * __expf(om - mn);
            m = mn;
        }
        if (m16 == 0) {
            int row = wl * 16 + quad * 4 + r;
            part2[row * 4 + g] = make_float2(m, s);
        }
    }
    __syncthreads();

    if (tid < 64) {
        float M = -INFINITY;
#pragma unroll
        for (int q = 0; q < 4; ++q) M = fmaxf(M, part2[tid * 4 + q].x);
        float S = 0.f;
#pragma unroll
        for (int q = 0; q < 4; ++q)
            S += part2[tid * 4 + q].y * __expf(part2[tid * 4 + q].x - M);
        float rowval = ws[DIAG_OFF + i0 + tid] - (M + logf(S));
#pragma unroll
        for (int mask = 32; mask > 0; mask >>= 1)
            rowval += __shfl_xor(rowval, mask);
        if (tid == 0) {
            atomicAdd(ws + ACC_OFF, rowval);
            __threadfence();
            unsigned old = atomicAdd((unsigned*)(ws + TICKET_OFF), 1u);
            if (old == 63u) {
                __threadfence();
                float acc = __hip_atomic_load(ws + ACC_OFF, __ATOMIC_RELAXED,
                                              __HIP_MEMORY_SCOPE_AGENT);
                out[0] = -acc / (float)B_TOT;
            }
        }
    }
}

extern "C" void kernel_launch(void* const* d_in, const int* in_sizes, int n_in,
                              void* d_out, int out_size, void* d_ws, size_t ws_size,
                              hipStream_t stream) {
    const float* zw_0   = (const float*)d_in[0];
    const float* zw_1   = (const float*)d_in[1];
    const float* c      = (const float*)d_in[2];
    const float* Wk_w   = (const float*)d_in[3];
    const float* Wk_b   = (const float*)d_in[4];
    const float* Ww0_w  = (const float*)d_in[5];
    const float* Ww0_b  = (const float*)d_in[6];
    const float* Ww1_w  = (const float*)d_in[7];
    const float* Ww1_b  = (const float*)d_in[8];
    const float* lin0_w = (const float*)d_in[9];
    const float* lin0_b = (const float*)d_in[10];
    const float* lin1_w = (const float*)d_in[11];
    const float* lin1_b = (const float*)d_in[12];
    const float* a0_1w  = (const float*)d_in[13];
    const float* a0_1b  = (const float*)d_in[14];
    const float* a0_2w  = (const float*)d_in[15];
    const float* a0_2b  = (const float*)d_in[16];
    const float* a1_1w  = (const float*)d_in[17];
    const float* a1_1b  = (const float*)d_in[18];
    const float* a1_2w  = (const float*)d_in[19];
    const float* a1_2b  = (const float*)d_in[20];
    float* ws  = (float*)d_ws;
    float* out = (float*)d_out;

    k1<<<256, 256, 0, stream>>>(zw_0, zw_1, c, Wk_w, Wk_b,
                                Ww0_w, Ww0_b, Ww1_w, Ww1_b,
                                lin0_w, lin0_b, lin1_w, lin1_b,
                                a0_1w, a0_1b, a0_2w, a0_2b,
                                a1_1w, a1_1b, a1_2w, a1_2b, ws);
    k2<<<256, 256, 0, stream>>>(ws);
    k3<<<64, 1024, 0, stream>>>(ws, out);
}

// Round 7
// 141.301 us; speedup vs baseline: 1.9331x; 1.2386x over previous
//
#include <hip/hip_runtime.h>
#include <math.h>

#define B_TOT 4096
#define B_HALF 2048

// ws float offsets.  bf16 4096x128 = 524288 halves = 262144 FLOATS.
#define ZWB_OFF    0          // bf16 4096*128  -> [0, 262144)
#define EV_OFF     262144     // 4096: e_i = exp(s_i)
#define VV_OFF     266240     // 4096*128 f32 -> [.., 790528)
#define BASE_OFF   790528     // 4096*128 f32 -> [.., 1314816)
#define PSTAT_OFF  1314816    // 256 * 129 -> [.., 1347840)
#define PREDB_OFF  1347840    // bf16 4096*128 -> [.., 1609984)
#define DIAG_OFF   1609984    // 4096 -> [.., 1614080)
#define PART_OFF   1614080    // 4096 rows * 8 chunks * float2 -> [.., 1679616)

typedef __bf16 bf16x8 __attribute__((ext_vector_type(8)));
typedef float  f32x4  __attribute__((ext_vector_type(4)));

__device__ __forceinline__ unsigned short f2bf(float f) {
    unsigned u = __float_as_uint(f);
    u = u + 0x7fffu + ((u >> 16) & 1u);   // RNE
    return (unsigned short)(u >> 16);
}
__device__ __forceinline__ float bf2f(unsigned short h) {
    return __uint_as_float(((unsigned)h) << 16);
}

// ---------------------------------------------------------------------------
// K1: per 16-row block: zt=relu(zw@lw^T+lb) (LDS only), e=exp(score),
// v = zt@Ww^T -> VV, base = c@Wk^T + Wk_b + Ww_b -> BASE, zw->bf16,
// block partials (E_b, U_b = sum e*v) -> PSTAT. No atomics.
// ---------------------------------------------------------------------------
__global__ __launch_bounds__(256)
void k1(const float* __restrict__ zw0, const float* __restrict__ zw1,
        const float* __restrict__ c,
        const float* __restrict__ Wk_w, const float* __restrict__ Wk_b,
        const float* __restrict__ Ww0_w, const float* __restrict__ Ww0_b,
        const float* __restrict__ Ww1_w, const float* __restrict__ Ww1_b,
        const float* __restrict__ lin0_w, const float* __restrict__ lin0_b,
        const float* __restrict__ lin1_w, const float* __restrict__ lin1_b,
        const float* __restrict__ a0_1w, const float* __restrict__ a0_1b,
        const float* __restrict__ a0_2w, const float* __restrict__ a0_2b,
        const float* __restrict__ a1_1w, const float* __restrict__ a1_1b,
        const float* __restrict__ a1_2w, const float* __restrict__ a1_2b,
        float* __restrict__ ws) {
    __shared__ float lws[8448];    // lin_w 64x132
    __shared__ float zws[2112];    // zw 16x132
    __shared__ float ztl[1088];    // zt 16x68
    __shared__ float a1s[2176];    // a1w 32x68
    __shared__ float wbuf[8704];   // Wk then Ww, 128x68
    __shared__ float cl[1088];     // c 16x68
    __shared__ float el[16];
    __shared__ float part[256];
    int tid = threadIdx.x;
    int b = blockIdx.x;
    int base = b * 16;
    int g = (base >= B_HALF);
    const float* lw = g ? lin1_w : lin0_w;
    const float* lb = g ? lin1_b : lin0_b;
    const float* w1 = g ? a1_1w : a0_1w;
    const float* b1 = g ? a1_1b : a0_1b;
    const float* w2 = g ? a1_2w : a0_2w;
    const float* b2 = g ? a1_2b : a0_2b;
    const float* Ww  = g ? Ww1_w : Ww0_w;
    const float* Wwb = g ? Ww1_b : Ww0_b;
    unsigned short* zwb = (unsigned short*)(ws + ZWB_OFF);

    const float4* lw4 = (const float4*)lw;
    for (int i = tid; i < 2048; i += 256) {
        int o = i >> 5, k4 = i & 31;
        ((float4*)(lws + o * 132))[k4] = lw4[i];
    }
    for (int i = tid; i < 512; i += 256) {
        int r = i >> 5, k4 = i & 31;
        int gi = base + r;
        const float* zr = (gi < B_HALF) ? (zw0 + (size_t)gi * 128)
                                        : (zw1 + (size_t)(gi - B_HALF) * 128);
        float4 v = ((const float4*)zr)[k4];
        ((float4*)(zws + r * 132))[k4] = v;
        uint2 p;
        p.x = (unsigned)f2bf(v.x) | ((unsigned)f2bf(v.y) << 16);
        p.y = (unsigned)f2bf(v.z) | ((unsigned)f2bf(v.w) << 16);
        ((uint2*)(zwb + (size_t)gi * 128))[k4] = p;
    }
    const float4* w14 = (const float4*)w1;
    for (int i = tid; i < 512; i += 256) {
        int o = i >> 4, k4 = i & 15;
        ((float4*)(a1s + o * 68))[k4] = w14[i];
    }
    if (tid < 256) {
        int r = tid >> 4, k4 = tid & 15;
        ((float4*)(cl + r * 68))[k4] = ((const float4*)(c + (size_t)(base + r) * 64))[k4];
    }
    const float4* Wk4 = (const float4*)Wk_w;
    for (int i = tid; i < 2048; i += 256) {
        int o = i >> 4, k4 = i & 15;
        ((float4*)(wbuf + o * 68))[k4] = Wk4[i];
    }
    __syncthreads();

    {
        int o = tid & 63, rgrp = tid >> 6;
        float bias = lb[o];
        float acc[4] = {bias, bias, bias, bias};
        const float4* wrow = (const float4*)(lws + o * 132);
        const float4* zr0 = (const float4*)(zws + (rgrp + 0) * 132);
        const float4* zr1 = (const float4*)(zws + (rgrp + 4) * 132);
        const float4* zr2 = (const float4*)(zws + (rgrp + 8) * 132);
        const float4* zr3 = (const float4*)(zws + (rgrp + 12) * 132);
#pragma unroll 4
        for (int k4 = 0; k4 < 32; ++k4) {
            float4 wv = wrow[k4];
            float4 z0 = zr0[k4], z1 = zr1[k4], z2 = zr2[k4], z3 = zr3[k4];
            acc[0] = fmaf(wv.x, z0.x, fmaf(wv.y, z0.y, fmaf(wv.z, z0.z, fmaf(wv.w, z0.w, acc[0]))));
            acc[1] = fmaf(wv.x, z1.x, fmaf(wv.y, z1.y, fmaf(wv.z, z1.z, fmaf(wv.w, z1.w, acc[1]))));
            acc[2] = fmaf(wv.x, z2.x, fmaf(wv.y, z2.y, fmaf(wv.z, z2.z, fmaf(wv.w, z2.w, acc[2]))));
            acc[3] = fmaf(wv.x, z3.x, fmaf(wv.y, z3.y, fmaf(wv.z, z3.z, fmaf(wv.w, z3.w, acc[3]))));
        }
#pragma unroll
        for (int rr = 0; rr < 4; ++rr)
            ztl[(rgrp + rr * 4) * 68 + o] = fmaxf(acc[rr], 0.f);
    }
    __syncthreads();

    {
        int o2 = tid & 31, r2 = tid >> 5;
        const float4* arow = (const float4*)(a1s + o2 * 68);
#pragma unroll
        for (int rpass = 0; rpass < 2; ++rpass) {
            int row = r2 + rpass * 8;
            float a = b1[o2];
            const float4* zt4 = (const float4*)(ztl + row * 68);
#pragma unroll 4
            for (int k4 = 0; k4 < 16; ++k4) {
                float4 wv = arow[k4];
                float4 zv = zt4[k4];
                a = fmaf(wv.x, zv.x, fmaf(wv.y, zv.y, fmaf(wv.z, zv.z, fmaf(wv.w, zv.w, a))));
            }
            float h = tanhf(a) * w2[o2];
#pragma unroll
            for (int mask = 16; mask > 0; mask >>= 1) h += __shfl_xor(h, mask);
            if (o2 == 0) {
                float e = __expf(h + b2[0]);
                el[row] = e;
                ws[EV_OFF + base + row] = e;
            }
        }
    }

    {
        int o = tid & 127, rsel = tid >> 7;
        float bias = Wk_b[o] + Wwb[o];
        float acc[8] = {bias, bias, bias, bias, bias, bias, bias, bias};
        const float4* krow = (const float4*)(wbuf + o * 68);
#pragma unroll 4
        for (int k4 = 0; k4 < 16; ++k4) {
            float4 kv = krow[k4];
#pragma unroll
            for (int j = 0; j < 8; ++j) {
                float4 cv = ((const float4*)(cl + (rsel + j * 2) * 68))[k4];
                acc[j] = fmaf(kv.x, cv.x, fmaf(kv.y, cv.y, fmaf(kv.z, cv.z, fmaf(kv.w, cv.w, acc[j]))));
            }
        }
#pragma unroll
        for (int j = 0; j < 8; ++j)
            ws[BASE_OFF + (size_t)(base + rsel + j * 2) * 128 + o] = acc[j];
    }
    __syncthreads();

    const float4* Ww4 = (const float4*)Ww;
    for (int i = tid; i < 2048; i += 256) {
        int o = i >> 4, k4 = i & 15;
        ((float4*)(wbuf + o * 68))[k4] = Ww4[i];
    }
    __syncthreads();

    {
        int o = tid & 127, rsel = tid >> 7;
        float acc[8] = {0.f, 0.f, 0.f, 0.f, 0.f, 0.f, 0.f, 0.f};
        const float4* wrow = (const float4*)(wbuf + o * 68);
#pragma unroll 4
        for (int k4 = 0; k4 < 16; ++k4) {
            float4 wv = wrow[k4];
#pragma unroll
            for (int j = 0; j < 8; ++j) {
                float4 pv = ((const float4*)(ztl + (rsel + j * 2) * 68))[k4];
                acc[j] = fmaf(wv.x, pv.x, fmaf(wv.y, pv.y, fmaf(wv.z, pv.z, fmaf(wv.w, pv.w, acc[j]))));
            }
        }
        float p = 0.f;
#pragma unroll
        for (int j = 0; j < 8; ++j) {
            ws[VV_OFF + (size_t)(base + rsel + j * 2) * 128 + o] = acc[j];
            p = fmaf(el[rsel + j * 2], acc[j], p);
        }
        part[tid] = p;
    }
    __syncthreads();
    if (tid < 128)
        ws[PSTAT_OFF + (size_t)b * 129 + 1 + tid] = part[tid] + part[tid + 128];
    if (tid == 128) {
        float E = 0.f;
#pragma unroll
        for (int r = 0; r < 16; ++r) E += el[r];
        ws[PSTAT_OFF + (size_t)b * 129] = E;
    }
}

// ---------------------------------------------------------------------------
// K2: reduce group partials (E,U[128]); pred = (U - e*v)/(E-e) + base -> bf16;
// diag[i] = dot(zw_i, pred_i).
// ---------------------------------------------------------------------------
__global__ __launch_bounds__(256)
void k2(float* __restrict__ ws) {
    __shared__ float us[132];
    int tid = threadIdx.x;
    int b = blockIdx.x;
    int base = b * 16;
    int g = (b >= 128);
    unsigned short* zwb   = (unsigned short*)(ws + ZWB_OFF);
    unsigned short* predb = (unsigned short*)(ws + PREDB_OFF);

    if (tid < 129) {
        const float* ps = ws + PSTAT_OFF + (size_t)g * 128 * 129 + tid;
        float acc = 0.f;
#pragma unroll 8
        for (int q = 0; q < 128; ++q) acc += ps[(size_t)q * 129];
        us[tid] = acc;
    }
    __syncthreads();

    float E = us[0];
    int r = tid >> 4, s16 = tid & 15;
    int gi = base + r;
    float er = ws[EV_OFF + gi];
    float inv = 1.f / (E - er);
    int o8 = s16 * 8;
    const float4* v4 = (const float4*)(ws + VV_OFF + (size_t)gi * 128 + o8);
    const float4* b4 = (const float4*)(ws + BASE_OFF + (size_t)gi * 128 + o8);
    float pr[8];
#pragma unroll
    for (int h = 0; h < 2; ++h) {
        float4 vv = v4[h], bb = b4[h];
        pr[h * 4 + 0] = (us[1 + o8 + h * 4 + 0] - er * vv.x) * inv + bb.x;
        pr[h * 4 + 1] = (us[1 + o8 + h * 4 + 1] - er * vv.y) * inv + bb.y;
        pr[h * 4 + 2] = (us[1 + o8 + h * 4 + 2] - er * vv.z) * inv + bb.z;
        pr[h * 4 + 3] = (us[1 + o8 + h * 4 + 3] - er * vv.w) * inv + bb.w;
    }
    uint4 pk;
    pk.x = (unsigned)f2bf(pr[0]) | ((unsigned)f2bf(pr[1]) << 16);
    pk.y = (unsigned)f2bf(pr[2]) | ((unsigned)f2bf(pr[3]) << 16);
    pk.z = (unsigned)f2bf(pr[4]) | ((unsigned)f2bf(pr[5]) << 16);
    pk.w = (unsigned)f2bf(pr[6]) | ((unsigned)f2bf(pr[7]) << 16);
    ((uint4*)(predb + (size_t)gi * 128))[s16] = pk;

    uint4 zz = ((const uint4*)(zwb + (size_t)gi * 128))[s16];
    const unsigned* zu = (const unsigned*)&zz;
    float d = 0.f;
#pragma unroll
    for (int q = 0; q < 4; ++q) {
        d = fmaf(bf2f((unsigned short)(zu[q] & 0xffff)), pr[q * 2], d);
        d = fmaf(bf2f((unsigned short)(zu[q] >> 16)), pr[q * 2 + 1], d);
    }
#pragma unroll
    for (int mask = 8; mask > 0; mask >>= 1) d += __shfl_xor(d, mask);
    if (s16 == 0) ws[DIAG_OFF + gi] = d;
}

// ---------------------------------------------------------------------------
// K3: 256 blocks x 512 thr (8 waves). Block = 128 i-rows x 512 j.
// Wave (rowg, jsub): 64 rows (A in registers) x 128 j, B fragments loaded
// DIRECTLY from global/L2 (no LDS in main loop), prefetch 1 tile ahead.
// Per-lane online (m,s)[atile][r] over its col-class; cross-lane merge at end;
// per-block 4-jsub merge in LDS -> PART[row][jchunk].
// ---------------------------------------------------------------------------
__global__ __launch_bounds__(512, 2)
void k3(float* __restrict__ ws) {
    __shared__ float2 part2[128 * 4];
    int tid = threadIdx.x;
    int b = blockIdx.x;
    int ic = b >> 3, jc = b & 7;
    int i0 = ic * 128;
    int w = tid >> 6, lane = tid & 63;
    int rowg = w >> 2, jsub = w & 3;
    int rowbase = i0 + rowg * 64;
    int jbase = jc * 512 + jsub * 128;
    int m16 = lane & 15, quad = lane >> 4;
    const unsigned short* zwb   = (const unsigned short*)(ws + ZWB_OFF);
    const unsigned short* predb = (const unsigned short*)(ws + PREDB_OFF);

    // A fragments: 64 rows x 128 k in registers (64 VGPRs)
    bf16x8 af[4][4];
#pragma unroll
    for (int a = 0; a < 4; ++a)
#pragma unroll
        for (int kk = 0; kk < 4; ++kk)
            af[a][kk] = *((const bf16x8*)(zwb +
                (size_t)(rowbase + a * 16 + m16) * 128 + kk * 32 + quad * 8));

    float m_run[4][4], s_run[4][4];
#pragma unroll
    for (int a = 0; a < 4; ++a)
#pragma unroll
        for (int r = 0; r < 4; ++r) { m_run[a][r] = -INFINITY; s_run[a][r] = 0.f; }

    // prefetch tile 0
    bf16x8 pf[4];
#pragma unroll
    for (int kk = 0; kk < 4; ++kk)
        pf[kk] = *((const bf16x8*)(predb +
            (size_t)(jbase + m16) * 128 + kk * 32 + quad * 8));

    for (int jt = 0; jt < 8; ++jt) {
        bf16x8 bf[4];
#pragma unroll
        for (int kk = 0; kk < 4; ++kk) bf[kk] = pf[kk];
        if (jt < 7) {
            int jrow = jbase + (jt + 1) * 16 + m16;
#pragma unroll
            for (int kk = 0; kk < 4; ++kk)
                pf[kk] = *((const bf16x8*)(predb +
                    (size_t)jrow * 128 + kk * 32 + quad * 8));
        }
        f32x4 acc[4];
#pragma unroll
        for (int a = 0; a < 4; ++a) acc[a] = (f32x4){0.f, 0.f, 0.f, 0.f};
#pragma unroll
        for (int kk = 0; kk < 4; ++kk)
#pragma unroll
            for (int a = 0; a < 4; ++a)
                acc[a] = __builtin_amdgcn_mfma_f32_16x16x32_bf16(af[a][kk], bf[kk], acc[a], 0, 0, 0);
#pragma unroll
        for (int a = 0; a < 4; ++a)
#pragma unroll
            for (int r = 0; r < 4; ++r) {
                float v = acc[a][r];
                float mn = fmaxf(m_run[a][r], v);
                s_run[a][r] = s_run[a][r] * __expf(m_run[a][r] - mn) + __expf(v - mn);
                m_run[a][r] = mn;
            }
    }

    // cross-lane merge over the 16 col-classes (m16)
#pragma unroll
    for (int a = 0; a < 4; ++a)
#pragma unroll
        for (int r = 0; r < 4; ++r) {
            float m = m_run[a][r], s = s_run[a][r];
#pragma unroll
            for (int mask = 1; mask < 16; mask <<= 1) {
                float om = __shfl_xor(m, mask);
                float os = __shfl_xor(s, mask);
                float mn = fmaxf(m, om);
                s = s * __expf(m - mn) + os * __expf(om - mn);
                m = mn;
            }
            if (m16 == 0) {
                int rib = rowg * 64 + a * 16 + quad * 4 + r;
                part2[rib * 4 + jsub] = make_float2(m, s);
            }
        }
    __syncthreads();

    if (tid < 128) {
        float M = -INFINITY;
#pragma unroll
        for (int q = 0; q < 4; ++q) M = fmaxf(M, part2[tid * 4 + q].x);
        float S = 0.f;
#pragma unroll
        for (int q = 0; q < 4; ++q)
            S += part2[tid * 4 + q].y * __expf(part2[tid * 4 + q].x - M);
        ((float2*)(ws + PART_OFF))[(size_t)(i0 + tid) * 8 + jc] = make_float2(M, S);
    }
}

// ---------------------------------------------------------------------------
// K4: single block: per row merge 8 chunk partials -> lse; rowval = diag - lse;
// reduce -> out. No atomics.
// ---------------------------------------------------------------------------
__global__ __launch_bounds__(1024)
void k4(const float* __restrict__ ws, float* __restrict__ out) {
    __shared__ float red[1024];
    int tid = threadIdx.x;
    float acc = 0.f;
    for (int r = tid; r < B_TOT; r += 1024) {
        const float2* p = (const float2*)(ws + PART_OFF) + (size_t)r * 8;
        float M = -INFINITY;
#pragma unroll
        for (int q = 0; q < 8; ++q) M = fmaxf(M, p[q].x);
        float S = 0.f;
#pragma unroll
        for (int q = 0; q < 8; ++q) S += p[q].y * __expf(p[q].x - M);
        acc += ws[DIAG_OFF + r] - (M + logf(S));
    }
    red[tid] = acc;
    __syncthreads();
    for (int o = 512; o > 0; o >>= 1) {
        if (tid < o) red[tid] += red[tid + o];
        __syncthreads();
    }
    if (tid == 0) out[0] = -red[0] / (float)B_TOT;
}

extern "C" void kernel_launch(void* const* d_in, const int* in_sizes, int n_in,
                              void* d_out, int out_size, void* d_ws, size_t ws_size,
                              hipStream_t stream) {
    const float* zw_0   = (const float*)d_in[0];
    const float* zw_1   = (const float*)d_in[1];
    const float* c      = (const float*)d_in[2];
    const float* Wk_w   = (const float*)d_in[3];
    const float* Wk_b   = (const float*)d_in[4];
    const float* Ww0_w  = (const float*)d_in[5];
    const float* Ww0_b  = (const float*)d_in[6];
    const float* Ww1_w  = (const float*)d_in[7];
    const float* Ww1_b  = (const float*)d_in[8];
    const float* lin0_w = (const float*)d_in[9];
    const float* lin0_b = (const float*)d_in[10];
    const float* lin1_w = (const float*)d_in[11];
    const float* lin1_b = (const float*)d_in[12];
    const float* a0_1w  = (const float*)d_in[13];
    const float* a0_1b  = (const float*)d_in[14];
    const float* a0_2w  = (const float*)d_in[15];
    const float* a0_2b  = (const float*)d_in[16];
    const float* a1_1w  = (const float*)d_in[17];
    const float* a1_1b  = (const float*)d_in[18];
    const float* a1_2w  = (const float*)d_in[19];
    const float* a1_2b  = (const float*)d_in[20];
    float* ws  = (float*)d_ws;
    float* out = (float*)d_out;

    k1<<<256, 256, 0, stream>>>(zw_0, zw_1, c, Wk_w, Wk_b,
                                Ww0_w, Ww0_b, Ww1_w, Ww1_b,
                                lin0_w, lin0_b, lin1_w, lin1_b,
                                a0_1w, a0_1b, a0_2w, a0_2b,
                                a1_1w, a1_1b, a1_2w, a1_2b, ws);
    k2<<<256, 256, 0, stream>>>(ws);
    k3<<<256, 512, 0, stream>>>(ws);
    k4<<<1, 1024, 0, stream>>>(ws, out);
}